// Round 8
// baseline (575.420 us; speedup 1.0000x reference)
//
#include <hip/hip_runtime.h>
#include <hip/hip_bf16.h>
#include <stdint.h>

// Problem constants (batch==1)
#define CIN   512
#define COUT  512
#define HH    256
#define WW    256
#define NPX   (HH*WW)          // 65536
#define KTAP  9

typedef __attribute__((ext_vector_type(8))) short bf16x8;   // 8 bf16 (4 VGPRs)
typedef __attribute__((ext_vector_type(4))) float f32x4;    // MFMA C/D frag

// fp32 -> bf16 bits (round-to-nearest-even via __float2bfloat16)
__device__ __forceinline__ ushort f2bfu(float v) {
  __hip_bfloat16 b = __float2bfloat16(v);
  return *reinterpret_cast<ushort*>(&b);
}

// ---- async global->LDS, 16B per lane. LDS dest must be wave-uniform base;
// HW writes base + lane*16. Global src is per-lane. ----
__device__ __forceinline__ void gload_lds16(const void* g, void* l) {
  __builtin_amdgcn_global_load_lds(
      (const __attribute__((address_space(1))) uint32_t*)g,
      (__attribute__((address_space(3))) uint32_t*)l,
      16, 0, 0);
}

// ---------------------------------------------------------------------------
// Kernel 1: demod + weight prep.
// weights: (1, COUT, CIN, 3, 3) fp32.  Out: wprep[tap][co][cin] bf16.
// Writes cin-coalesced per tap; reads contiguous 36B chunks (L1-resident
// after the sum pass).
// ---------------------------------------------------------------------------
__global__ void demod_prep_kernel(const float* __restrict__ w,
                                  __hip_bfloat16* __restrict__ wprep) {
  const int co = blockIdx.x;
  const int t  = threadIdx.x;                  // 256 threads
  const float* wc = w + (size_t)co * (CIN * 9);

  float s = 0.f;
  for (int i = t; i < CIN * 9; i += 256) { float v = wc[i]; s += v * v; }
  #pragma unroll
  for (int off = 32; off > 0; off >>= 1) s += __shfl_down(s, off);
  __shared__ float ps[4];
  if ((t & 63) == 0) ps[t >> 6] = s;
  __syncthreads();
  const float tot = ps[0] + ps[1] + ps[2] + ps[3];
  const float d = rsqrtf(tot + 1e-8f);

  #pragma unroll
  for (int rep = 0; rep < 2; ++rep) {
    const int cin = t + rep * 256;
    float v[9];
    #pragma unroll
    for (int tap = 0; tap < 9; ++tap) v[tap] = wc[cin * 9 + tap];
    #pragma unroll
    for (int tap = 0; tap < 9; ++tap)
      wprep[(size_t)tap * (COUT * CIN) + (size_t)co * CIN + cin] =
          __float2bfloat16(v[tap] * d);
  }
}

// ---------------------------------------------------------------------------
// Kernel 2 (v3): NCHW fp32 -> NHWC bf16 via LDS tile transpose.
// Tile: 64 px x 64 cin.  grid = 256 h x 4 px-tiles x 8 cin-tiles = 8192.
// v3 changes vs v2 (which ran ~1.1 TB/s):
//  - LOAD side is now float4 (16B/lane): lane reads 4 px at ONE channel;
//    16-lane groups cover a 256B contiguous segment.  (v2 did 16 scalar
//    4B loads/thread — the ~2.5x penalty of Common-mistake #2.)
//  - T is [c][px] pitch 76 ushorts (152B rows: 8B-aligned; 38 dwords = 6
//    mod 32 -> worst ~4-way bank conflicts instead of v2's 8-way).
//  - WRITE side unchanged pattern: 16 lanes x 8B = 128B contiguous cin.
// ---------------------------------------------------------------------------
__global__ void to_hwc_kernel(const float* __restrict__ in,
                              __hip_bfloat16* __restrict__ hwc) {
  __shared__ ushort T[64][76];                 // [c][px], 9.7KB
  const int bid = blockIdx.x;
  const int h  = bid >> 5;
  const int p0 = ((bid >> 3) & 3) * 64;
  const int c0 = (bid & 7) * 64;
  const int t  = threadIdx.x;

  // load: thread -> (channel band, 4-px quad); float4 per pass
  const int pxq = (t & 15) * 4;                // 4-px quad within tile
  const int cl  = t >> 4;                      // channel within 16-band
  #pragma unroll
  for (int pass = 0; pass < 4; ++pass) {
    const int c = c0 + pass * 16 + cl;
    const float4 v =
        *(const float4*)&in[(size_t)c * NPX + (size_t)h * WW + p0 + pxq];
    ushort4 u;
    u.x = f2bfu(v.x); u.y = f2bfu(v.y); u.z = f2bfu(v.z); u.w = f2bfu(v.w);
    *(ushort4*)&T[pass * 16 + cl][pxq] = u;    // 8B LDS write, aligned
  }
  __syncthreads();

  // write: thread -> (px = it*16 + t>>4, c4 = (t&15)*4); gather 4 u16 rows
  const int c4 = (t & 15) * 4;
  #pragma unroll
  for (int it = 0; it < 4; ++it) {
    const int px = it * 16 + (t >> 4);
    ushort4 v;
    v.x = T[c4 + 0][px];
    v.y = T[c4 + 1][px];
    v.z = T[c4 + 2][px];
    v.w = T[c4 + 3][px];
    *(ushort4*)&hwc[((size_t)h * WW + p0 + px) * CIN + c0 + c4] = v;
  }
}

// ---------------------------------------------------------------------------
// Kernel 3: conv as 9 shifted GEMMs, 128x128 tile, BK=32, MFMA 16x16x32 bf16.
// grid: 2048 blocks = 4 co-tiles x 512 px-tiles.  256 threads = 4 waves 2x2.
// XCD-aware bijective swizzle (2048 % 8 == 0): the 4 co-sibling blocks
// sharing one B panel land on the SAME XCD's L2 (FETCH 1.22GB -> 0.34GB
// measured r7).  UNCHANGED from r7 run.
// ---------------------------------------------------------------------------
__global__ void conv_mfma_kernel(const __hip_bfloat16* __restrict__ hwc,
                                 const __hip_bfloat16* __restrict__ wprep,
                                 const __hip_bfloat16* __restrict__ zp,
                                 float* __restrict__ out) {
  __shared__ __align__(16) __hip_bfloat16 As[128 * 32];   // [co_row][k] 8KB
  __shared__ __align__(16) __hip_bfloat16 Bs[128 * 32];   // [px_row][k] 8KB

  const int t    = threadIdx.x;
  const int wave = t >> 6, lane = t & 63;
  const int kg   = lane >> 4, lr = lane & 15;
  const int wm   = wave >> 1, wn = wave & 1;

  const int bid = blockIdx.x;
  const int wg  = ((bid & 7) << 8) | (bid >> 3);   // 2048 = 8 * 256
  const int co0 = (wg & 3) * 128;
  const int pt  = wg >> 2;             // 0..511
  const int h   = pt >> 1;
  const int w0  = (pt & 1) * 128;

  const int srow = t >> 2;             // 0..63 (row within 64-row pass)
  const int scol = (t & 3) * 8;        // bf16 col offset

  __hip_bfloat16* Ab0 = &As[(wave * 64) * 8];
  __hip_bfloat16* Ab1 = &As[(256 + wave * 64) * 8];
  __hip_bfloat16* Bb0 = &Bs[(wave * 64) * 8];
  __hip_bfloat16* Bb1 = &Bs[(256 + wave * 64) * 8];

  f32x4 acc[4][4] = {};

  for (int tap = 0; tap < KTAP; ++tap) {
    const int dh = tap / 3 - 1, dw = tap % 3 - 1;
    const int hp = h + dh;
    if (hp < 0 || hp >= HH) continue;          // block-uniform padding skip

    const __hip_bfloat16* gw =
        wprep + (size_t)tap * (COUT * CIN) + (size_t)(co0 + srow) * CIN + scol;

    const int wc0 = w0 + dw + srow;            // pixel col, pass 0
    const int wc1 = wc0 + 64;                  // pixel col, pass 1
    const bool v0 = ((unsigned)wc0 < (unsigned)WW);
    const bool v1 = ((unsigned)wc1 < (unsigned)WW);
    const __hip_bfloat16* gb0 = hwc + ((long)hp * WW + wc0) * CIN + scol;
    const __hip_bfloat16* gb1 = hwc + ((long)hp * WW + wc1) * CIN + scol;

    for (int k0 = 0; k0 < CIN; k0 += 32) {
      __syncthreads();                          // prev iter's frag reads done
      gload_lds16(gw + k0,             Ab0);
      gload_lds16(gw + k0 + 64 * CIN,  Ab1);
      gload_lds16(v0 ? (const void*)(gb0 + k0) : (const void*)zp, Bb0);
      gload_lds16(v1 ? (const void*)(gb1 + k0) : (const void*)zp, Bb1);
      __syncthreads();                          // staging complete

      bf16x8 af[4], bf[4];
      #pragma unroll
      for (int mi = 0; mi < 4; ++mi)
        af[mi] = *(const bf16x8*)&As[(wm * 64 + mi * 16 + lr) * 32 + kg * 8];
      #pragma unroll
      for (int ni = 0; ni < 4; ++ni)
        bf[ni] = *(const bf16x8*)&Bs[(wn * 64 + ni * 16 + lr) * 32 + kg * 8];

      #pragma unroll
      for (int mi = 0; mi < 4; ++mi)
        #pragma unroll
        for (int ni = 0; ni < 4; ++ni)
          acc[mi][ni] = __builtin_amdgcn_mfma_f32_16x16x32_bf16(
              af[mi], bf[ni], acc[mi][ni], 0, 0, 0);
    }
  }

  // epilogue: C/D layout col=lane&15, row=(lane>>4)*4+j  [m89-verified]
  const long pxbase = (long)h * WW + w0;
  #pragma unroll
  for (int mi = 0; mi < 4; ++mi) {
    const int row = co0 + wm * 64 + mi * 16 + kg * 4;
    #pragma unroll
    for (int ni = 0; ni < 4; ++ni) {
      const long col = pxbase + wn * 64 + ni * 16 + lr;
      #pragma unroll
      for (int j = 0; j < 4; ++j)
        out[(long)(row + j) * NPX + col] = acc[mi][ni][j];
    }
  }
}

// ---------------------------------------------------------------------------
extern "C" void kernel_launch(void* const* d_in, const int* in_sizes, int n_in,
                              void* d_out, int out_size, void* d_ws, size_t ws_size,
                              hipStream_t stream) {
  const float* inp = (const float*)d_in[0];    // (1,512,256,256) fp32
  const float* wts = (const float*)d_in[1];    // (1,512,512,3,3) fp32
  float* out = (float*)d_out;                  // (1,512,256,256) fp32

  char* ws = (char*)d_ws;
  __hip_bfloat16* hwc   = (__hip_bfloat16*)ws;                       // 64 MB
  __hip_bfloat16* wprep = (__hip_bfloat16*)(ws + (size_t)NPX * CIN * 2);  // 4.5 MB
  __hip_bfloat16* zp    = (__hip_bfloat16*)(ws + (size_t)NPX * CIN * 2
                                               + (size_t)KTAP * COUT * CIN * 2);

  (void)hipMemsetAsync(zp, 0, 256, stream);    // zero page for padded lanes

  demod_prep_kernel<<<COUT, 256, 0, stream>>>(wts, wprep);
  to_hwc_kernel<<<HH * 32, 256, 0, stream>>>(inp, hwc);
  conv_mfma_kernel<<<(COUT / 128) * (NPX / 128), 256, 0, stream>>>(hwc, wprep, zp, out);
}

// Round 9
// 557.926 us; speedup vs baseline: 1.0314x; 1.0314x over previous
//
#include <hip/hip_runtime.h>
#include <hip/hip_bf16.h>
#include <stdint.h>

// Problem constants (batch==1)
#define CIN   512
#define COUT  512
#define HH    256
#define WW    256
#define NPX   (HH*WW)          // 65536
#define KTAP  9

typedef __attribute__((ext_vector_type(8))) short bf16x8;   // 8 bf16 (4 VGPRs)
typedef __attribute__((ext_vector_type(4))) float f32x4;    // MFMA C/D frag

// fp32 -> bf16 bits (round-to-nearest-even via __float2bfloat16)
__device__ __forceinline__ ushort f2bfu(float v) {
  __hip_bfloat16 b = __float2bfloat16(v);
  return *reinterpret_cast<ushort*>(&b);
}

// ---- async global->LDS, 16B per lane. LDS dest must be wave-uniform base;
// HW writes base + lane*16. Global src is per-lane. ----
__device__ __forceinline__ void gload_lds16(const void* g, void* l) {
  __builtin_amdgcn_global_load_lds(
      (const __attribute__((address_space(1))) uint32_t*)g,
      (__attribute__((address_space(3))) uint32_t*)l,
      16, 0, 0);
}

// ---------------------------------------------------------------------------
// Kernel 1: demod + weight prep (unchanged from r8).
// wprep[tap][co][cin] = w[co][cin][kh][kw] * rsqrt(sum_sq(w[co]) + 1e-8)
// ---------------------------------------------------------------------------
__global__ void demod_prep_kernel(const float* __restrict__ w,
                                  __hip_bfloat16* __restrict__ wprep) {
  const int co = blockIdx.x;
  const int t  = threadIdx.x;                  // 256 threads
  const float* wc = w + (size_t)co * (CIN * 9);

  float s = 0.f;
  for (int i = t; i < CIN * 9; i += 256) { float v = wc[i]; s += v * v; }
  #pragma unroll
  for (int off = 32; off > 0; off >>= 1) s += __shfl_down(s, off);
  __shared__ float ps[4];
  if ((t & 63) == 0) ps[t >> 6] = s;
  __syncthreads();
  const float tot = ps[0] + ps[1] + ps[2] + ps[3];
  const float d = rsqrtf(tot + 1e-8f);

  #pragma unroll
  for (int rep = 0; rep < 2; ++rep) {
    const int cin = t + rep * 256;
    float v[9];
    #pragma unroll
    for (int tap = 0; tap < 9; ++tap) v[tap] = wc[cin * 9 + tap];
    #pragma unroll
    for (int tap = 0; tap < 9; ++tap)
      wprep[(size_t)tap * (COUT * CIN) + (size_t)co * CIN + cin] =
          __float2bfloat16(v[tap] * d);
  }
}

// ---------------------------------------------------------------------------
// Kernel 2: NCHW fp32 -> NHWC bf16 (unchanged from r8, v3).
// ---------------------------------------------------------------------------
__global__ void to_hwc_kernel(const float* __restrict__ in,
                              __hip_bfloat16* __restrict__ hwc) {
  __shared__ ushort T[64][76];
  const int bid = blockIdx.x;
  const int h  = bid >> 5;
  const int p0 = ((bid >> 3) & 3) * 64;
  const int c0 = (bid & 7) * 64;
  const int t  = threadIdx.x;

  const int pxq = (t & 15) * 4;
  const int cl  = t >> 4;
  #pragma unroll
  for (int pass = 0; pass < 4; ++pass) {
    const int c = c0 + pass * 16 + cl;
    const float4 v =
        *(const float4*)&in[(size_t)c * NPX + (size_t)h * WW + p0 + pxq];
    ushort4 u;
    u.x = f2bfu(v.x); u.y = f2bfu(v.y); u.z = f2bfu(v.z); u.w = f2bfu(v.w);
    *(ushort4*)&T[pass * 16 + cl][pxq] = u;
  }
  __syncthreads();

  const int c4 = (t & 15) * 4;
  #pragma unroll
  for (int it = 0; it < 4; ++it) {
    const int px = it * 16 + (t >> 4);
    ushort4 v;
    v.x = T[c4 + 0][px];
    v.y = T[c4 + 1][px];
    v.z = T[c4 + 2][px];
    v.w = T[c4 + 3][px];
    *(ushort4*)&hwc[((size_t)h * WW + p0 + px) * CIN + c0 + c4] = v;
  }
}

// ---------------------------------------------------------------------------
// Kernel 3 (v3): conv as 9 shifted GEMMs — 256x256 tile, BK=64, 8-phase
// schedule (T2 swizzle + T3/T4 counted vmcnt + T5 setprio), per m201 template.
//
// Geometry: 512 thr = 8 waves (2M x 4N); per-wave 128co x 64px; acc[8][4].
// px-tile = one full image row (256 px) -> h-edge taps are a contiguous
// tap range (tap_base..tap_base+nv-1), w-edges via per-lane zero-page.
// LDS: A/B each [2buf][2half][128 rows][64 k] bf16 = 64KB -> 128KB total.
//   A half mh = rows read only in quadrant phases (mh,*);
//   B half nh = px strips read only in quadrant phases (*,nh).
// Phase p of K-tile j = C-quadrant (mh,nh) x K=64: 12 ds_read_b128, 16 MFMA.
// Stage schedule (1 half-tile = 2 gload_lds per thread, per phase), iter t:
//   ph1 A(2t+1,mh1)->buf1   ph2 B(2t+1,nh1)->buf1    (slots freed prev iter)
//   ph3 A(2t+2,mh0)->buf0   ph4 B(2t+2,nh0)->buf0    (freed after ph2/ph3)
//   ph5 A(2t+2,mh1)->buf0   ph6 B(2t+2,nh1)->buf0    (freed after ph4)
//   ph7 A(2t+3,mh0)->buf1   ph8 B(2t+3,nh0)->buf1    (freed after ph6/ph7)
// Every half staged >=2 phases after its slot's last read, >=4 phases before
// first consume.  vmcnt(4) at end of ph4 and ph8 only (2 loads/phase in
// flight x last 2 phases) — never drains to 0 in the main loop.
// T2 swizzle: LDS ushort idx ^= (row&7)<<3 on reads; gload dest stays linear,
// global source takes the inverse permutation (rule #21).
// ---------------------------------------------------------------------------
__global__ __launch_bounds__(512, 2)
void conv_mfma8_kernel(const __hip_bfloat16* __restrict__ hwc,
                       const __hip_bfloat16* __restrict__ wprep,
                       const __hip_bfloat16* __restrict__ zp,
                       float* __restrict__ out) {
  __shared__ __align__(16) ushort Al[2][2][128 * 64];   // 64KB
  __shared__ __align__(16) ushort Bl[2][2][128 * 64];   // 64KB

  const int t    = threadIdx.x;
  const int lane = t & 63, kg = lane >> 4, lr = lane & 15;
  const int wave = t >> 6, wm = wave >> 2, wn = wave & 3;
  const int wuni = t & ~63;                    // wave*64

  // XCD swizzle: 512 = 8 XCD chunks of 64; co-siblings adjacent in wg
  const int bid = blockIdx.x;
  const int wg  = ((bid & 7) << 6) | (bid >> 3);
  const int co0 = (wg & 1) * 256;
  const int h   = wg >> 1;

  const int tap_base = (h == 0) ? 3 : 0;
  const int nv  = (h == 0 || h == HH - 1) ? 6 : 9;
  const int NTK = nv * 8;                      // BK=64 K-tiles
  const int iters = NTK >> 1;

  const ushort* __restrict__ W = (const ushort*)wprep;
  const ushort* __restrict__ X = (const ushort*)hwc;

  auto stageA = [&](int kt, int mh, int buf) {
    const int tap = tap_base + (kt >> 3);
    const int k0  = (kt & 7) * 64;
    const ushort* wp = W + (size_t)tap * (COUT * CIN) + k0;
    #pragma unroll
    for (int j = 0; j < 2; ++j) {
      const int c   = j * 512 + t;
      const int row = c >> 3;
      const int co  = co0 + ((row >> 6) << 7) + mh * 64 + (row & 63);
      const int cg8 = ((c & 7) ^ (row & 7)) << 3;      // inverse swizzle
      gload_lds16(wp + (size_t)co * CIN + cg8,
                  &Al[buf][mh][(j * 512 + wuni) * 8]);
    }
  };
  auto stageB = [&](int kt, int nh, int buf) {
    const int tap = tap_base + (kt >> 3);
    const int k0  = (kt & 7) * 64;
    const int d3  = tap / 3;
    const int dw  = tap - d3 * 3 - 1;
    const int hp  = h + d3 - 1;                // in-range for valid taps
    const ushort* bp = X + (size_t)hp * WW * CIN + k0;
    #pragma unroll
    for (int j = 0; j < 2; ++j) {
      const int c   = j * 512 + t;
      const int row = c >> 3;
      const int px  = ((row >> 5) << 6) + nh * 32 + (row & 31);
      const int cg8 = ((c & 7) ^ (row & 7)) << 3;
      const int pxs = px + dw;
      const ushort* src = ((unsigned)pxs < (unsigned)WW)
                        ? bp + (size_t)pxs * CIN + cg8
                        : (const ushort*)zp;   // w-edge zero page
      gload_lds16(src, &Bl[buf][nh][(j * 512 + wuni) * 8]);
    }
  };

  f32x4 acc[8][4] = {};

  // prologue: K-tile 0 fully + early halves of K-tile 1 (12 loads/thread)
  stageA(0, 0, 0); stageA(0, 1, 0); stageB(0, 0, 0); stageB(0, 1, 0);
  stageA(1, 0, 1); stageB(1, 0, 1);
  asm volatile("s_waitcnt vmcnt(4)" ::: "memory");   // K0 landed
  __builtin_amdgcn_s_barrier();

#define PHASE(MH, NH, BUF, STAGE_STMT, VM_STMT) do {                          \
    bf16x8 af[4][2], bf[2][2];                                                \
    _Pragma("unroll") for (int mi = 0; mi < 4; ++mi)                          \
      _Pragma("unroll") for (int kk = 0; kk < 2; ++kk)                        \
        af[mi][kk] = *(const bf16x8*)&Al[BUF][MH][                            \
            ((wm * 64 + mi * 16 + lr) * 64 + kk * 32 + kg * 8)                \
            ^ ((lr & 7) << 3)];                                               \
    _Pragma("unroll") for (int nj = 0; nj < 2; ++nj)                          \
      _Pragma("unroll") for (int kk = 0; kk < 2; ++kk)                        \
        bf[nj][kk] = *(const bf16x8*)&Bl[BUF][NH][                            \
            ((wn * 32 + nj * 16 + lr) * 64 + kk * 32 + kg * 8)                \
            ^ ((lr & 7) << 3)];                                               \
    STAGE_STMT;                                                               \
    __builtin_amdgcn_s_barrier();                                             \
    asm volatile("s_waitcnt lgkmcnt(0)" ::: "memory");                        \
    __builtin_amdgcn_sched_barrier(0);                                        \
    __builtin_amdgcn_s_setprio(1);                                            \
    _Pragma("unroll") for (int mi = 0; mi < 4; ++mi)                          \
      _Pragma("unroll") for (int nj = 0; nj < 2; ++nj)                        \
        _Pragma("unroll") for (int kk = 0; kk < 2; ++kk)                      \
          acc[MH * 4 + mi][NH * 2 + nj] =                                     \
              __builtin_amdgcn_mfma_f32_16x16x32_bf16(                        \
                  af[mi][kk], bf[nj][kk], acc[MH * 4 + mi][NH * 2 + nj],      \
                  0, 0, 0);                                                   \
    __builtin_amdgcn_s_setprio(0);                                            \
    VM_STMT;                                                                  \
    __builtin_amdgcn_s_barrier();                                             \
  } while (0)

  for (int it = 0; it < iters; ++it) {
    const int ka = 2 * it + 1;                               // never OOB
    const int kb = (2 * it + 2 < NTK) ? 2 * it + 2 : NTK - 1; // clamped tail
    const int kc = (2 * it + 3 < NTK) ? 2 * it + 3 : NTK - 1;
    PHASE(0, 0, 0, stageA(ka, 1, 1), );
    PHASE(0, 1, 0, stageB(ka, 1, 1), );
    PHASE(1, 0, 0, stageA(kb, 0, 0), );
    PHASE(1, 1, 0, stageB(kb, 0, 0),
          asm volatile("s_waitcnt vmcnt(4)" ::: "memory"));
    PHASE(0, 0, 1, stageA(kb, 1, 0), );
    PHASE(0, 1, 1, stageB(kb, 1, 0), );
    PHASE(1, 0, 1, stageA(kc, 0, 1), );
    PHASE(1, 1, 1, stageB(kc, 0, 1),
          asm volatile("s_waitcnt vmcnt(4)" ::: "memory"));
  }
#undef PHASE

  // epilogue: C/D layout col=lane&15, row=(lane>>4)*4+j  [m89-verified]
  const size_t pxb = (size_t)h * WW;
  #pragma unroll
  for (int mh = 0; mh < 2; ++mh)
    #pragma unroll
    for (int mi = 0; mi < 4; ++mi) {
      const int r0 = co0 + wm * 128 + mh * 64 + mi * 16 + kg * 4;
      #pragma unroll
      for (int nh = 0; nh < 2; ++nh)
        #pragma unroll
        for (int nj = 0; nj < 2; ++nj) {
          const int px = wn * 64 + nh * 32 + nj * 16 + lr;
          #pragma unroll
          for (int j = 0; j < 4; ++j)
            out[(size_t)(r0 + j) * NPX + pxb + px] = acc[mh * 4 + mi][nh * 2 + nj][j];
        }
    }
}

// ---------------------------------------------------------------------------
extern "C" void kernel_launch(void* const* d_in, const int* in_sizes, int n_in,
                              void* d_out, int out_size, void* d_ws, size_t ws_size,
                              hipStream_t stream) {
  const float* inp = (const float*)d_in[0];    // (1,512,256,256) fp32
  const float* wts = (const float*)d_in[1];    // (1,512,512,3,3) fp32
  float* out = (float*)d_out;                  // (1,512,256,256) fp32

  char* ws = (char*)d_ws;
  __hip_bfloat16* hwc   = (__hip_bfloat16*)ws;                       // 64 MB
  __hip_bfloat16* wprep = (__hip_bfloat16*)(ws + (size_t)NPX * CIN * 2);  // 4.5 MB
  __hip_bfloat16* zp    = (__hip_bfloat16*)(ws + (size_t)NPX * CIN * 2
                                               + (size_t)KTAP * COUT * CIN * 2);

  (void)hipMemsetAsync(zp, 0, 256, stream);    // zero page for padded lanes

  demod_prep_kernel<<<COUT, 256, 0, stream>>>(wts, wprep);
  to_hwc_kernel<<<HH * 32, 256, 0, stream>>>(inp, hwc);
  conv_mfma8_kernel<<<512, 512, 0, stream>>>(hwc, wprep, zp, out);
}